// Round 1
// baseline (277.153 us; speedup 1.0000x reference)
//
#include <hip/hip_runtime.h>
#include <hip/hip_bf16.h>

typedef __attribute__((ext_vector_type(8))) short bf16x8;
typedef __attribute__((ext_vector_type(4))) float floatx4;

#define B_TOT 4096
#define NKEEP 25
#define DIM 128
#define SCALE_Q 0.17677669529663687f

#define NCB  (262144)    // 64 g * 4 h * 16 grp * 64 lane
#define NW1  (6144)      // 24 ot * 4 kk * 64 lane
#define NW2  (2048)      // 8 ot * 4 kk * 64 lane

__device__ __forceinline__ short f2bs(float f) {
  __hip_bfloat16 h = __float2bfloat16(f);
  return *reinterpret_cast<short*>(&h);
}

__device__ __forceinline__ bf16x8 ld8(const float* p) {
  const float4 u = reinterpret_cast<const float4*>(p)[0];
  const float4 v = reinterpret_cast<const float4*>(p)[1];
  bf16x8 r;
  r[0] = f2bs(u.x); r[1] = f2bs(u.y); r[2] = f2bs(u.z); r[3] = f2bs(u.w);
  r[4] = f2bs(v.x); r[5] = f2bs(v.y); r[6] = f2bs(v.z); r[7] = f2bs(v.w);
  return r;
}

// direct-to-LDS 16B copy: per-lane global src, wave-uniform LDS dest (+lane*16)
__device__ __forceinline__ void gld16(const float* g, float* s) {
  __builtin_amdgcn_global_load_lds(
      (const __attribute__((address_space(1))) unsigned int*)g,
      (__attribute__((address_space(3))) unsigned int*)s, 16, 0, 0);
}

// ---------------- k_prep: combs + weight fragments only (xs eliminated) ----
__global__ __launch_bounds__(256) void k_prep(
    const float* __restrict__ w1, const float* __restrict__ w2,
    const float* __restrict__ mask, const int* __restrict__ ids,
    const int* __restrict__ rel, const float* __restrict__ btab,
    short* __restrict__ w1s, short* __restrict__ w2s,
    float* __restrict__ combs)
{
  const int t = blockIdx.x * 256 + threadIdx.x;
  if (t < NCB) {
    const int g = t >> 12, rest = t & 4095;
    const int h = rest >> 10, j = rest & 1023;
    const int grp = j >> 6, lane = j & 63;
    const int mt = grp >> 3, nt = (grp >> 2) & 1, rr = grp & 3;
    const int quad = lane >> 4, l16 = lane & 15;
    const int m = mt * 16 + quad * 4 + rr, n = nt * 16 + l16;
    float v = 0.f;
    if (m < 25 && n < 25) {
      const int im = ids[g * 25 + m], in = ids[g * 25 + n];
      v = btab[rel[im * 49 + in] * 4 + h] + mask[((size_t)g * 49 + im) * 49 + in];
    }
    combs[t] = v;
  } else if (t < NCB + NW1) {
    const int c = t - NCB;
    const int ot = c >> 8, rem = c & 255, kk = rem >> 6, l = rem & 63;
    const int quad = l >> 4, l16 = l & 15;
    *reinterpret_cast<bf16x8*>(w1s + (size_t)c * 8) =
        ld8(w1 + (size_t)(ot * 16 + l16) * DIM + kk * 32 + quad * 8);
  } else {
    const int c = t - (NCB + NW1);
    const int ot = c >> 8, rem = c & 255, kk = rem >> 6, l = rem & 63;
    const int quad = l >> 4, l16 = l & 15;
    *reinterpret_cast<bf16x8*>(w2s + (size_t)c * 8) =
        ld8(w2 + (size_t)(ot * 16 + l16) * DIM + kk * 32 + quad * 8);
  }
}

// ---------------- k_fused ---------------------------------------------------
// 4 windows/block, 4 waves (wave h = head h). x staged fp32 via
// global_load_lds into fragment-ordered XF (ping-pong), bf16 cvt at read.
// XF unit u = p*512 + (mt*4+kk)*64 + lane, 16B each:
//   floats x[win][tok(mt,l16)][kk*32 + quad*8 + p*4 .. +4], tok clamped to 24.
// Register diet for 3 blocks/CU: QK weights persistent (64 regs); V weights,
// combs tile and proj weights JIT-loaded (L2-hot); V packed to bf16 early.
__global__ __launch_bounds__(256, 3) void k_fused(
    const float* __restrict__ x, const short* __restrict__ w1s,
    const short* __restrict__ w2s, const float* __restrict__ qkvb,
    const float* __restrict__ pb, const float* __restrict__ combs,
    float* __restrict__ out)
{
  __shared__ __align__(16) float XF[2][4096];   // 2 x 16KB fp32 staging
  __shared__ __align__(16) short TL[10240];     // 8 tiles of 32x40 shorts

  const int tid = threadIdx.x;
  const int wv = tid >> 6, l = tid & 63, l16 = l & 15, quad = l >> 4;
  const int h = wv;
  short* T1 = TL + wv * 2560;
  short* T2 = T1 + 1280;
  const int win0 = blockIdx.x * 4;
  const floatx4 zero = {0.f, 0.f, 0.f, 0.f};

  // stage one window of x (fp32) into XF[dsthalf]; 4 gld16 per thread
  auto stage = [&](int win, float* dst) {
#pragma unroll
    for (int ps = 0; ps < 4; ++ps) {
      const int u = ps * 256 + wv * 64 + l;
      const int p = u >> 9, i = (u >> 6) & 7;
      const int mt = i >> 2, kk = i & 3;
      int tok = mt * 16 + l16; if (tok > 24) tok = 24;
      gld16(x + (size_t)win * 3200 + tok * 128 + kk * 32 + quad * 8 + p * 4,
            dst + (size_t)(ps * 256 + wv * 64) * 4);
    }
  };

  // persistent QK weight fragments (64 VGPRs)
  bf16x8 wqk[4][4];
  {
    const int otqk[4] = {2 * h, 2 * h + 1, 8 + 2 * h, 9 + 2 * h};
#pragma unroll
    for (int t = 0; t < 4; ++t)
#pragma unroll
      for (int kk = 0; kk < 4; ++kk)
        wqk[t][kk] = *reinterpret_cast<const bf16x8*>(
            w1s + ((size_t)(otqk[t] * 4 + kk) * 64 + l) * 8);
  }
  float qb6[6];
#pragma unroll
  for (int t = 0; t < 2; ++t) {
    qb6[t]     = qkvb[(2 * h + t) * 16 + l16];
    qb6[2 + t] = qkvb[(8 + 2 * h + t) * 16 + l16];
    qb6[4 + t] = qkvb[(16 + 2 * h + t) * 16 + l16];
  }
  float pbf[2];
#pragma unroll
  for (int nt = 0; nt < 2; ++nt) pbf[nt] = pb[h * 32 + nt * 16 + l16];

  stage(win0, &XF[0][0]);

  for (int r = 0; r < 4; ++r) {
    const int win = win0 + r, half = r & 1, g = win & 63;

    __syncthreads();   // barrier1: prev proj reads done; XF[half] staged

    // ---- A fragments: fp32 from XF -> bf16 (conflict-free b128 reads) ----
    bf16x8 aW[2][4];
#pragma unroll
    for (int kk = 0; kk < 4; ++kk)
#pragma unroll
      for (int mt = 0; mt < 2; ++mt) {
        const int i = mt * 4 + kk;
        const float4 f0 = *reinterpret_cast<const float4*>(&XF[half][(i * 64 + l) * 4]);
        const float4 f1 = *reinterpret_cast<const float4*>(&XF[half][2048 + (i * 64 + l) * 4]);
        bf16x8 a;
        a[0] = f2bs(f0.x); a[1] = f2bs(f0.y); a[2] = f2bs(f0.z); a[3] = f2bs(f0.w);
        a[4] = f2bs(f1.x); a[5] = f2bs(f1.y); a[6] = f2bs(f1.z); a[7] = f2bs(f1.w);
        aW[mt][kk] = a;
      }

    // issue next-window stage NOW: in flight across QK+V+attn, drains at barrier2
    if (r < 3) stage(win + 1, &XF[1 - half][0]);

    // ---- QK GEMM (32 MFMA) ----
    floatx4 aqk[2][4];
#pragma unroll
    for (int mt = 0; mt < 2; ++mt)
#pragma unroll
      for (int t = 0; t < 4; ++t) aqk[mt][t] = zero;
#pragma unroll
    for (int kk = 0; kk < 4; ++kk)
#pragma unroll
      for (int t = 0; t < 4; ++t) {
        aqk[0][t] = __builtin_amdgcn_mfma_f32_16x16x32_bf16(aW[0][kk], wqk[t][kk], aqk[0][t], 0, 0, 0);
        aqk[1][t] = __builtin_amdgcn_mfma_f32_16x16x32_bf16(aW[1][kk], wqk[t][kk], aqk[1][t], 0, 0, 0);
      }

    // V weights JIT (L2-hot; latency covered by QK epilogue)
    bf16x8 wv1[2][4];
#pragma unroll
    for (int nt = 0; nt < 2; ++nt)
#pragma unroll
      for (int kk = 0; kk < 4; ++kk)
        wv1[nt][kk] = *reinterpret_cast<const bf16x8*>(
            w1s + ((size_t)((16 + 2 * h + nt) * 4 + kk) * 64 + l) * 8);

    // Q -> T1, K -> T2
#pragma unroll
    for (int t = 0; t < 2; ++t)
#pragma unroll
      for (int mt = 0; mt < 2; ++mt)
#pragma unroll
        for (int rr = 0; rr < 4; ++rr) {
          const int row = (mt * 16 + quad * 4 + rr) * 40 + t * 16 + l16;
          T1[row] = f2bs((aqk[mt][t][rr] + qb6[t]) * SCALE_Q);
          T2[row] = f2bs(aqk[mt][2 + t][rr] + qb6[2 + t]);
        }

    // ---- V GEMM (16 MFMA) ----
    floatx4 av[2][2];
#pragma unroll
    for (int mt = 0; mt < 2; ++mt)
#pragma unroll
      for (int t = 0; t < 2; ++t) av[mt][t] = zero;
#pragma unroll
    for (int kk = 0; kk < 4; ++kk)
#pragma unroll
      for (int t = 0; t < 2; ++t) {
        av[0][t] = __builtin_amdgcn_mfma_f32_16x16x32_bf16(aW[0][kk], wv1[t][kk], av[0][t], 0, 0, 0);
        av[1][t] = __builtin_amdgcn_mfma_f32_16x16x32_bf16(aW[1][kk], wv1[t][kk], av[1][t], 0, 0, 0);
      }

    // bias+mask tile JIT (L2-hot; covered by V epilogue + QK^T)
    float cmb[2][2][4];
#pragma unroll
    for (int mt = 0; mt < 2; ++mt)
#pragma unroll
      for (int nt = 0; nt < 2; ++nt)
#pragma unroll
        for (int rr = 0; rr < 4; ++rr)
          cmb[mt][nt][rr] = combs[(((size_t)g * 4 + h) * 16 + mt * 8 + nt * 4 + rr) * 64 + l];

    // V -> packed bf16 in regs (8 VGPRs instead of 16)
    short4 vpack[2][2];
#pragma unroll
    for (int t = 0; t < 2; ++t)
#pragma unroll
      for (int mt = 0; mt < 2; ++mt) {
        short4 pk;
        pk.x = f2bs(av[mt][t][0] + qb6[4 + t]);
        pk.y = f2bs(av[mt][t][1] + qb6[4 + t]);
        pk.z = f2bs(av[mt][t][2] + qb6[4 + t]);
        pk.w = f2bs(av[mt][t][3] + qb6[4 + t]);
        vpack[t][mt] = pk;
      }

    // ---- attention (wave-local) ----
    bf16x8 aq[2], bk[2];
#pragma unroll
    for (int t = 0; t < 2; ++t) {
      aq[t] = *reinterpret_cast<const bf16x8*>(&T1[(t * 16 + l16) * 40 + quad * 8]);
      bk[t] = *reinterpret_cast<const bf16x8*>(&T2[(t * 16 + l16) * 40 + quad * 8]);
    }
    floatx4 S[2][2];
#pragma unroll
    for (int mt = 0; mt < 2; ++mt)
#pragma unroll
      for (int nt = 0; nt < 2; ++nt)
        S[mt][nt] = __builtin_amdgcn_mfma_f32_16x16x32_bf16(aq[mt], bk[nt], zero, 0, 0, 0);

#pragma unroll
    for (int mt = 0; mt < 2; ++mt) {
      float s[2][4];
#pragma unroll
      for (int nt = 0; nt < 2; ++nt)
#pragma unroll
        for (int rr = 0; rr < 4; ++rr) {
          const int n = nt * 16 + l16;
          s[nt][rr] = (n < 25) ? S[mt][nt][rr] + cmb[mt][nt][rr] : -1e30f;
        }
#pragma unroll
      for (int rr = 0; rr < 4; ++rr) {
        float mx = fmaxf(s[0][rr], s[1][rr]);
#pragma unroll
        for (int off = 1; off < 16; off <<= 1) mx = fmaxf(mx, __shfl_xor(mx, off));
        const float e0 = __expf(s[0][rr] - mx);
        const float e1 = __expf(s[1][rr] - mx);
        float sm = e0 + e1;
#pragma unroll
        for (int off = 1; off < 16; off <<= 1) sm += __shfl_xor(sm, off);
        const float inv = 1.f / sm;
        const int row = (mt * 16 + quad * 4 + rr) * 40;
        T2[row + l16]      = f2bs(e0 * inv);   // P over K (K consumed)
        T2[row + 16 + l16] = f2bs(e1 * inv);
      }
    }
    // VT over Q in T1 (Q consumed): [d][tok]
#pragma unroll
    for (int t = 0; t < 2; ++t)
#pragma unroll
      for (int mt = 0; mt < 2; ++mt)
        *reinterpret_cast<short4*>(&T1[(t * 16 + l16) * 40 + mt * 16 + quad * 4]) = vpack[t][mt];

    bf16x8 ap[2], bv[2];
#pragma unroll
    for (int t = 0; t < 2; ++t) {
      ap[t] = *reinterpret_cast<const bf16x8*>(&T2[(t * 16 + l16) * 40 + quad * 8]);
      bv[t] = *reinterpret_cast<const bf16x8*>(&T1[(t * 16 + l16) * 40 + quad * 8]);
    }
    floatx4 O[2][2];
#pragma unroll
    for (int mt = 0; mt < 2; ++mt)
#pragma unroll
      for (int nt = 0; nt < 2; ++nt)
        O[mt][nt] = __builtin_amdgcn_mfma_f32_16x16x32_bf16(ap[mt], bv[nt], zero, 0, 0, 0);

    // proj weights JIT (L2-hot; covered by O epilogue + barrier2)
    bf16x8 w2f[2][4];
#pragma unroll
    for (int nt = 0; nt < 2; ++nt)
#pragma unroll
      for (int kk = 0; kk < 4; ++kk)
        w2f[nt][kk] = *reinterpret_cast<const bf16x8*>(
            w2s + ((size_t)((h * 2 + nt) * 4 + kk) * 64 + l) * 8);

    // O -> T1 rows [tok][d_local]
#pragma unroll
    for (int mt = 0; mt < 2; ++mt)
#pragma unroll
      for (int rr = 0; rr < 4; ++rr)
#pragma unroll
        for (int nt = 0; nt < 2; ++nt)
          T1[(mt * 16 + quad * 4 + rr) * 40 + nt * 16 + l16] = f2bs(O[mt][nt][rr]);

    __syncthreads();   // barrier2: all O tiles ready; next-window stage drained

    // ---- proj: wave h -> out cols [h*32, h*32+32) ----
    floatx4 acc2[2][2];
#pragma unroll
    for (int mt = 0; mt < 2; ++mt)
#pragma unroll
      for (int nt = 0; nt < 2; ++nt) acc2[mt][nt] = zero;
#pragma unroll
    for (int kk = 0; kk < 4; ++kk) {
      const bf16x8 a20 = *reinterpret_cast<const bf16x8*>(&TL[kk * 2560 + l16 * 40 + quad * 8]);
      const bf16x8 a21 = *reinterpret_cast<const bf16x8*>(&TL[kk * 2560 + (16 + l16) * 40 + quad * 8]);
#pragma unroll
      for (int nt = 0; nt < 2; ++nt) {
        acc2[0][nt] = __builtin_amdgcn_mfma_f32_16x16x32_bf16(a20, w2f[nt][kk], acc2[0][nt], 0, 0, 0);
        acc2[1][nt] = __builtin_amdgcn_mfma_f32_16x16x32_bf16(a21, w2f[nt][kk], acc2[1][nt], 0, 0, 0);
      }
    }
#pragma unroll
    for (int mt = 0; mt < 2; ++mt)
#pragma unroll
      for (int rr = 0; rr < 4; ++rr) {
        const int m = mt * 16 + quad * 4 + rr;
        if (m < 25) {
#pragma unroll
          for (int nt = 0; nt < 2; ++nt)
            out[((size_t)win * NKEEP + m) * DIM + h * 32 + nt * 16 + l16] =
                acc2[mt][nt][rr] + pbf[nt];
        }
      }
  }
}

extern "C" void kernel_launch(void* const* d_in, const int* in_sizes, int n_in,
                              void* d_out, int out_size, void* d_ws, size_t ws_size,
                              hipStream_t stream) {
  const float* x    = (const float*)d_in[0];
  const float* mask = (const float*)d_in[1];
  const int*   ids  = (const int*)d_in[2];
  const float* qkvw = (const float*)d_in[3];
  const float* qkvb = (const float*)d_in[4];
  const float* pw   = (const float*)d_in[5];
  const float* pb   = (const float*)d_in[6];
  const float* btab = (const float*)d_in[7];
  const int*   rel  = (const int*)d_in[8];

  short* w1s   = (short*)d_ws;                      // 96 KB
  short* w2s   = w1s + (size_t)NW1 * 8;             // 32 KB
  float* combs = (float*)(w2s + (size_t)NW2 * 8);   // 1 MB
  float* out   = (float*)d_out;

  k_prep <<<dim3((NCB + NW1 + NW2) / 256), 256, 0, stream>>>(
      qkvw, pw, mask, ids, rel, btab, w1s, w2s, combs);
  k_fused<<<dim3(B_TOT / 4), 256, 0, stream>>>(
      x, w1s, w2s, qkvb, pb, combs, out);
}

// Round 2
// 231.456 us; speedup vs baseline: 1.1974x; 1.1974x over previous
//
#include <hip/hip_runtime.h>
#include <hip/hip_bf16.h>

typedef __attribute__((ext_vector_type(8))) short bf16x8;
typedef __attribute__((ext_vector_type(4))) float floatx4;

#define B_TOT 4096
#define NKEEP 25
#define DIM 128
#define SCALE_Q 0.17677669529663687f

// ---------------- k_prep: swizzle everything into fragment order ----------
#define NXS  (2097152)   // 4096 * 512
#define NCB  (262144)    // 64 * 4 * 16 * 64
#define NW1  (6144)
#define NW2  (2048)

__device__ __forceinline__ short f2bs(float f) {
  __hip_bfloat16 h = __float2bfloat16(f);
  return *reinterpret_cast<short*>(&h);
}

__device__ __forceinline__ bf16x8 ld8(const float* p) {
  const float4 u = reinterpret_cast<const float4*>(p)[0];
  const float4 v = reinterpret_cast<const float4*>(p)[1];
  bf16x8 r;
  r[0] = f2bs(u.x); r[1] = f2bs(u.y); r[2] = f2bs(u.z); r[3] = f2bs(u.w);
  r[4] = f2bs(v.x); r[5] = f2bs(v.y); r[6] = f2bs(v.z); r[7] = f2bs(v.w);
  return r;
}

__global__ __launch_bounds__(256) void k_prep(
    const float* __restrict__ x, const float* __restrict__ w1,
    const float* __restrict__ w2, const float* __restrict__ mask,
    const int* __restrict__ ids, const int* __restrict__ rel,
    const float* __restrict__ btab,
    short* __restrict__ xs, short* __restrict__ w1s,
    short* __restrict__ w2s, float* __restrict__ combs)
{
  size_t t = (size_t)blockIdx.x * 256 + threadIdx.x;  // grid exactly covers
  if (t < NXS) {
    const int win = (int)(t >> 9), c = (int)(t & 511);
    const int i = c >> 6, l = c & 63;
    const int mt = i >> 2, kk = i & 3, quad = l >> 4, l16 = l & 15;
    int tok = mt * 16 + l16; if (tok > 24) tok = 24;
    const float* p = x + (size_t)win * (NKEEP * DIM) + tok * DIM + kk * 32 + quad * 8;
    *reinterpret_cast<bf16x8*>(xs + t * 8) = ld8(p);
  } else if (t < NXS + NCB) {
    const size_t u = t - NXS;
    const int g = (int)(u >> 12), rest = (int)(u & 4095);
    const int h = rest >> 10, j = rest & 1023;
    const int grp = j >> 6, lane = j & 63;
    const int mt = grp >> 3, nt = (grp >> 2) & 1, rr = grp & 3;
    const int quad = lane >> 4, l16 = lane & 15;
    const int m = mt * 16 + quad * 4 + rr, n = nt * 16 + l16;
    float v = 0.f;
    if (m < 25 && n < 25) {
      const int im = ids[g * 25 + m], in = ids[g * 25 + n];
      v = btab[rel[im * 49 + in] * 4 + h] + mask[((size_t)g * 49 + im) * 49 + in];
    }
    combs[u] = v;
  } else if (t < NXS + NCB + NW1) {
    const int c = (int)(t - (NXS + NCB));
    const int ot = c >> 8, rem = c & 255, kk = rem >> 6, l = rem & 63;
    const int quad = l >> 4, l16 = l & 15;
    *reinterpret_cast<bf16x8*>(w1s + (size_t)c * 8) =
        ld8(w1 + (size_t)(ot * 16 + l16) * DIM + kk * 32 + quad * 8);
  } else {
    const int c = (int)(t - (NXS + NCB + NW1));
    const int ot = c >> 8, rem = c & 255, kk = rem >> 6, l = rem & 63;
    const int quad = l >> 4, l16 = l & 15;
    *reinterpret_cast<bf16x8*>(w2s + (size_t)c * 8) =
        ld8(w2 + (size_t)(ot * 16 + l16) * DIM + kk * 32 + quad * 8);
  }
}

// ---------------- k_fused ---------------------------------------------------
// 4 windows/block, 4 waves (wave h = head h). xs fragment-ordered bf16,
// ping-pong staged via registers into XB. All global loads issued AFTER
// barrier1 at their phase site (nothing outstanding at barrier1 except prev
// proj stores). Weights JIT per pass (Q-pair / K-pair / V-pair / proj) so
// peak liveness stays ~136 < 168 cap -> 3 blocks/CU, no spill.
__global__ __launch_bounds__(256, 3) void k_fused(
    const short* __restrict__ xs, const short* __restrict__ w1s,
    const short* __restrict__ w2s, const float* __restrict__ qkvb,
    const float* __restrict__ pb, const float* __restrict__ combs,
    float* __restrict__ out)
{
  __shared__ __align__(16) short XB[8192];    // 2 x 512 chunks of 8 shorts
  __shared__ __align__(16) short TL[10240];   // 8 tiles of 32x40 shorts

  const int tid = threadIdx.x;
  const int wv = tid >> 6, l = tid & 63, l16 = l & 15, quad = l >> 4;
  const int h = wv;
  short* T1 = TL + wv * 2560;
  short* T2 = T1 + 1280;
  const int win0 = blockIdx.x * 4;
  const floatx4 zero = {0.f, 0.f, 0.f, 0.f};

  // persistent biases only (8 regs)
  float qb6[6];
#pragma unroll
  for (int t = 0; t < 2; ++t) {
    qb6[t]     = qkvb[(2 * h + t) * 16 + l16];
    qb6[2 + t] = qkvb[(8 + 2 * h + t) * 16 + l16];
    qb6[4 + t] = qkvb[(16 + 2 * h + t) * 16 + l16];
  }
  float pbf[2];
#pragma unroll
  for (int nt = 0; nt < 2; ++nt) pbf[nt] = pb[h * 32 + nt * 16 + l16];

  // stage window 0 into XB half 0
  {
    bf16x8 xg[2];
#pragma unroll
    for (int j = 0; j < 2; ++j) {
      const int c = wv * 128 + j * 64 + l;
      xg[j] = *reinterpret_cast<const bf16x8*>(xs + ((size_t)win0 * 512 + c) * 8);
    }
#pragma unroll
    for (int j = 0; j < 2; ++j) {
      const int c = wv * 128 + j * 64 + l;
      *reinterpret_cast<bf16x8*>(XB + c * 8) = xg[j];
    }
  }

  for (int r = 0; r < 4; ++r) {
    const int win = win0 + r, half = r & 1, g = win & 63;

    __syncthreads();   // barrier1: prev proj reads done; XB[half] visible

    // ---- A fragments from XB (8 conflict-free ds_read_b128, held 32 regs) ----
    bf16x8 aW[2][4];
#pragma unroll
    for (int kk = 0; kk < 4; ++kk)
#pragma unroll
      for (int mt = 0; mt < 2; ++mt)
        aW[mt][kk] = *reinterpret_cast<const bf16x8*>(
            XB + ((half * 512 + (mt * 4 + kk) * 64 + l)) * 8);

    // issue next-window stream NOW (consumed at stage-write before barrier2:
    // whole-round latency cover, no stall at any barrier)
    bf16x8 xg[2];
    if (r < 3) {
#pragma unroll
      for (int j = 0; j < 2; ++j) {
        const int c = wv * 128 + j * 64 + l;
        xg[j] = *reinterpret_cast<const bf16x8*>(xs + ((size_t)(win + 1) * 512 + c) * 8);
      }
    }

    // ---- Q pass (JIT weights, 16 MFMA) ----
    floatx4 accQ[2][2];
    {
      bf16x8 wq[2][4];
#pragma unroll
      for (int t = 0; t < 2; ++t)
#pragma unroll
        for (int kk = 0; kk < 4; ++kk)
          wq[t][kk] = *reinterpret_cast<const bf16x8*>(
              w1s + ((size_t)((2 * h + t) * 4 + kk) * 64 + l) * 8);
#pragma unroll
      for (int mt = 0; mt < 2; ++mt)
#pragma unroll
        for (int t = 0; t < 2; ++t) accQ[mt][t] = zero;
#pragma unroll
      for (int kk = 0; kk < 4; ++kk)
#pragma unroll
        for (int t = 0; t < 2; ++t) {
          accQ[0][t] = __builtin_amdgcn_mfma_f32_16x16x32_bf16(aW[0][kk], wq[t][kk], accQ[0][t], 0, 0, 0);
          accQ[1][t] = __builtin_amdgcn_mfma_f32_16x16x32_bf16(aW[1][kk], wq[t][kk], accQ[1][t], 0, 0, 0);
        }
    }
    // Q epilogue -> T1 (frees accQ)
#pragma unroll
    for (int t = 0; t < 2; ++t)
#pragma unroll
      for (int mt = 0; mt < 2; ++mt)
#pragma unroll
        for (int rr = 0; rr < 4; ++rr)
          T1[(mt * 16 + quad * 4 + rr) * 40 + t * 16 + l16] =
              f2bs((accQ[mt][t][rr] + qb6[t]) * SCALE_Q);

    // ---- K pass (16 MFMA) ----
    floatx4 accK[2][2];
    {
      bf16x8 wk[2][4];
#pragma unroll
      for (int t = 0; t < 2; ++t)
#pragma unroll
        for (int kk = 0; kk < 4; ++kk)
          wk[t][kk] = *reinterpret_cast<const bf16x8*>(
              w1s + ((size_t)((8 + 2 * h + t) * 4 + kk) * 64 + l) * 8);
#pragma unroll
      for (int mt = 0; mt < 2; ++mt)
#pragma unroll
        for (int t = 0; t < 2; ++t) accK[mt][t] = zero;
#pragma unroll
      for (int kk = 0; kk < 4; ++kk)
#pragma unroll
        for (int t = 0; t < 2; ++t) {
          accK[0][t] = __builtin_amdgcn_mfma_f32_16x16x32_bf16(aW[0][kk], wk[t][kk], accK[0][t], 0, 0, 0);
          accK[1][t] = __builtin_amdgcn_mfma_f32_16x16x32_bf16(aW[1][kk], wk[t][kk], accK[1][t], 0, 0, 0);
        }
    }
#pragma unroll
    for (int t = 0; t < 2; ++t)
#pragma unroll
      for (int mt = 0; mt < 2; ++mt)
#pragma unroll
        for (int rr = 0; rr < 4; ++rr)
          T2[(mt * 16 + quad * 4 + rr) * 40 + t * 16 + l16] =
              f2bs(accK[mt][t][rr] + qb6[2 + t]);

    // bias+mask tile JIT (L2-hot; covered by V pass + attention reads)
    float cmb[2][2][4];
#pragma unroll
    for (int mt = 0; mt < 2; ++mt)
#pragma unroll
      for (int nt = 0; nt < 2; ++nt)
#pragma unroll
        for (int rr = 0; rr < 4; ++rr)
          cmb[mt][nt][rr] =
              combs[(((size_t)g * 4 + h) * 16 + mt * 8 + nt * 4 + rr) * 64 + l];

    // ---- V pass (16 MFMA) -> packed bf16 in regs (8 regs) ----
    short4 vpack[2][2];
    {
      bf16x8 wvv[2][4];
#pragma unroll
      for (int t = 0; t < 2; ++t)
#pragma unroll
        for (int kk = 0; kk < 4; ++kk)
          wvv[t][kk] = *reinterpret_cast<const bf16x8*>(
              w1s + ((size_t)((16 + 2 * h + t) * 4 + kk) * 64 + l) * 8);
      floatx4 av[2][2];
#pragma unroll
      for (int mt = 0; mt < 2; ++mt)
#pragma unroll
        for (int t = 0; t < 2; ++t) av[mt][t] = zero;
#pragma unroll
      for (int kk = 0; kk < 4; ++kk)
#pragma unroll
        for (int t = 0; t < 2; ++t) {
          av[0][t] = __builtin_amdgcn_mfma_f32_16x16x32_bf16(aW[0][kk], wvv[t][kk], av[0][t], 0, 0, 0);
          av[1][t] = __builtin_amdgcn_mfma_f32_16x16x32_bf16(aW[1][kk], wvv[t][kk], av[1][t], 0, 0, 0);
        }
#pragma unroll
      for (int t = 0; t < 2; ++t)
#pragma unroll
        for (int mt = 0; mt < 2; ++mt) {
          short4 pk;
          pk.x = f2bs(av[mt][t][0] + qb6[4 + t]);
          pk.y = f2bs(av[mt][t][1] + qb6[4 + t]);
          pk.z = f2bs(av[mt][t][2] + qb6[4 + t]);
          pk.w = f2bs(av[mt][t][3] + qb6[4 + t]);
          vpack[t][mt] = pk;
        }
    }

    // ---- attention (wave-local) ----
    bf16x8 aq[2], bk[2];
#pragma unroll
    for (int t = 0; t < 2; ++t) {
      aq[t] = *reinterpret_cast<const bf16x8*>(&T1[(t * 16 + l16) * 40 + quad * 8]);
      bk[t] = *reinterpret_cast<const bf16x8*>(&T2[(t * 16 + l16) * 40 + quad * 8]);
    }
    floatx4 S[2][2];
#pragma unroll
    for (int mt = 0; mt < 2; ++mt)
#pragma unroll
      for (int nt = 0; nt < 2; ++nt)
        S[mt][nt] = __builtin_amdgcn_mfma_f32_16x16x32_bf16(aq[mt], bk[nt], zero, 0, 0, 0);

#pragma unroll
    for (int mt = 0; mt < 2; ++mt) {
      float s[2][4];
#pragma unroll
      for (int nt = 0; nt < 2; ++nt)
#pragma unroll
        for (int rr = 0; rr < 4; ++rr) {
          const int n = nt * 16 + l16;
          s[nt][rr] = (n < 25) ? S[mt][nt][rr] + cmb[mt][nt][rr] : -1e30f;
        }
#pragma unroll
      for (int rr = 0; rr < 4; ++rr) {
        float mx = fmaxf(s[0][rr], s[1][rr]);
#pragma unroll
        for (int off = 1; off < 16; off <<= 1) mx = fmaxf(mx, __shfl_xor(mx, off));
        const float e0 = __expf(s[0][rr] - mx);
        const float e1 = __expf(s[1][rr] - mx);
        float sm = e0 + e1;
#pragma unroll
        for (int off = 1; off < 16; off <<= 1) sm += __shfl_xor(sm, off);
        const float inv = 1.f / sm;
        const int row = (mt * 16 + quad * 4 + rr) * 40;
        T2[row + l16]      = f2bs(e0 * inv);   // P over K (K consumed)
        T2[row + 16 + l16] = f2bs(e1 * inv);
      }
    }
    // VT over Q in T1 (Q consumed): [d][tok]
#pragma unroll
    for (int t = 0; t < 2; ++t)
#pragma unroll
      for (int mt = 0; mt < 2; ++mt)
        *reinterpret_cast<short4*>(&T1[(t * 16 + l16) * 40 + mt * 16 + quad * 4]) = vpack[t][mt];

    bf16x8 ap[2], bv[2];
#pragma unroll
    for (int t = 0; t < 2; ++t) {
      ap[t] = *reinterpret_cast<const bf16x8*>(&T2[(t * 16 + l16) * 40 + quad * 8]);
      bv[t] = *reinterpret_cast<const bf16x8*>(&T1[(t * 16 + l16) * 40 + quad * 8]);
    }
    floatx4 O[2][2];
#pragma unroll
    for (int mt = 0; mt < 2; ++mt)
#pragma unroll
      for (int nt = 0; nt < 2; ++nt)
        O[mt][nt] = __builtin_amdgcn_mfma_f32_16x16x32_bf16(ap[mt], bv[nt], zero, 0, 0, 0);

    // O -> T1 rows [tok][d_local]
#pragma unroll
    for (int mt = 0; mt < 2; ++mt)
#pragma unroll
      for (int rr = 0; rr < 4; ++rr)
#pragma unroll
        for (int nt = 0; nt < 2; ++nt)
          T1[(mt * 16 + quad * 4 + rr) * 40 + nt * 16 + l16] = f2bs(O[mt][nt][rr]);

    // stage next window into the other XB half (vmcnt wait lands HERE,
    // ~a full round after issue)
    if (r < 3) {
#pragma unroll
      for (int j = 0; j < 2; ++j) {
        const int c = wv * 128 + j * 64 + l;
        *reinterpret_cast<bf16x8*>(XB + (((r + 1) & 1) * 512 + c) * 8) = xg[j];
      }
    }
    __syncthreads();   // barrier2: all O tiles ready, XB staged

    // ---- proj: wave h -> out cols [h*32, h*32+32); JIT proj weights ----
    bf16x8 w2f[2][4];
#pragma unroll
    for (int nt = 0; nt < 2; ++nt)
#pragma unroll
      for (int kk = 0; kk < 4; ++kk)
        w2f[nt][kk] = *reinterpret_cast<const bf16x8*>(
            w2s + ((size_t)((h * 2 + nt) * 4 + kk) * 64 + l) * 8);
    floatx4 acc2[2][2];
#pragma unroll
    for (int mt = 0; mt < 2; ++mt)
#pragma unroll
      for (int nt = 0; nt < 2; ++nt) acc2[mt][nt] = zero;
#pragma unroll
    for (int kk = 0; kk < 4; ++kk) {
      const bf16x8 a20 = *reinterpret_cast<const bf16x8*>(&TL[kk * 2560 + l16 * 40 + quad * 8]);
      const bf16x8 a21 = *reinterpret_cast<const bf16x8*>(&TL[kk * 2560 + (16 + l16) * 40 + quad * 8]);
#pragma unroll
      for (int nt = 0; nt < 2; ++nt) {
        acc2[0][nt] = __builtin_amdgcn_mfma_f32_16x16x32_bf16(a20, w2f[nt][kk], acc2[0][nt], 0, 0, 0);
        acc2[1][nt] = __builtin_amdgcn_mfma_f32_16x16x32_bf16(a21, w2f[nt][kk], acc2[1][nt], 0, 0, 0);
      }
    }
#pragma unroll
    for (int mt = 0; mt < 2; ++mt)
#pragma unroll
      for (int rr = 0; rr < 4; ++rr) {
        const int m = mt * 16 + quad * 4 + rr;
        if (m < 25) {
#pragma unroll
          for (int nt = 0; nt < 2; ++nt)
            out[((size_t)win * NKEEP + m) * DIM + h * 32 + nt * 16 + l16] =
                acc2[mt][nt][rr] + pbf[nt];
        }
      }
  }
}

extern "C" void kernel_launch(void* const* d_in, const int* in_sizes, int n_in,
                              void* d_out, int out_size, void* d_ws, size_t ws_size,
                              hipStream_t stream) {
  const float* x    = (const float*)d_in[0];
  const float* mask = (const float*)d_in[1];
  const int*   ids  = (const int*)d_in[2];
  const float* qkvw = (const float*)d_in[3];
  const float* qkvb = (const float*)d_in[4];
  const float* pw   = (const float*)d_in[5];
  const float* pb   = (const float*)d_in[6];
  const float* btab = (const float*)d_in[7];
  const int*   rel  = (const int*)d_in[8];

  short* xs    = (short*)d_ws;                        // 32 MB
  short* w1s   = xs + (size_t)NXS * 8;                // 96 KB
  short* w2s   = w1s + (size_t)NW1 * 8;               // 32 KB
  float* combs = (float*)(w2s + (size_t)NW2 * 8);     // 1 MB
  float* out   = (float*)d_out;

  const int prep_blocks = (NXS + NCB + NW1 + NW2) / 256;  // 9248
  k_prep <<<dim3(prep_blocks), 256, 0, stream>>>(
      x, qkvw, pw, mask, ids, rel, btab, xs, w1s, w2s, combs);
  k_fused<<<dim3(B_TOT / 4),   256, 0, stream>>>(
      xs, w1s, w2s, qkvb, pb, combs, out);
}

// Round 3
// 180.374 us; speedup vs baseline: 1.5365x; 1.2832x over previous
//
#include <hip/hip_runtime.h>
#include <hip/hip_bf16.h>

typedef __attribute__((ext_vector_type(8))) short bf16x8;
typedef __attribute__((ext_vector_type(4))) float floatx4;

#define B_TOT 4096
#define NKEEP 25
#define DIM 128
#define SCALE_Q 0.17677669529663687f

#define NCB  (262144)    // 64 g * 4 h * 16 grp * 64 lane
#define NW1  (6144)      // 24 ot * 4 kk * 64 lane
#define NW2  (2048)      // 8 ot * 4 kk * 64 lane

__device__ __forceinline__ short f2bs(float f) {
  __hip_bfloat16 h = __float2bfloat16(f);
  return *reinterpret_cast<short*>(&h);
}

__device__ __forceinline__ bf16x8 ld8(const float* p) {
  const float4 u = reinterpret_cast<const float4*>(p)[0];
  const float4 v = reinterpret_cast<const float4*>(p)[1];
  bf16x8 r;
  r[0] = f2bs(u.x); r[1] = f2bs(u.y); r[2] = f2bs(u.z); r[3] = f2bs(u.w);
  r[4] = f2bs(v.x); r[5] = f2bs(v.y); r[6] = f2bs(v.z); r[7] = f2bs(v.w);
  return r;
}

// ---------------- k_prep: combs + weight fragments only (xs eliminated) ----
__global__ __launch_bounds__(256) void k_prep(
    const float* __restrict__ w1, const float* __restrict__ w2,
    const float* __restrict__ mask, const int* __restrict__ ids,
    const int* __restrict__ rel, const float* __restrict__ btab,
    short* __restrict__ w1s, short* __restrict__ w2s,
    float* __restrict__ combs)
{
  const int t = blockIdx.x * 256 + threadIdx.x;
  if (t < NCB) {
    const int g = t >> 12, rest = t & 4095;
    const int h = rest >> 10, j = rest & 1023;
    const int grp = j >> 6, lane = j & 63;
    const int mt = grp >> 3, nt = (grp >> 2) & 1, rr = grp & 3;
    const int quad = lane >> 4, l16 = lane & 15;
    const int m = mt * 16 + quad * 4 + rr, n = nt * 16 + l16;
    float v = 0.f;
    if (m < 25 && n < 25) {
      const int im = ids[g * 25 + m], in = ids[g * 25 + n];
      v = btab[rel[im * 49 + in] * 4 + h] + mask[((size_t)g * 49 + im) * 49 + in];
    }
    combs[t] = v;
  } else if (t < NCB + NW1) {
    const int c = t - NCB;
    const int ot = c >> 8, rem = c & 255, kk = rem >> 6, l = rem & 63;
    const int quad = l >> 4, l16 = l & 15;
    *reinterpret_cast<bf16x8*>(w1s + (size_t)c * 8) =
        ld8(w1 + (size_t)(ot * 16 + l16) * DIM + kk * 32 + quad * 8);
  } else {
    const int c = t - (NCB + NW1);
    const int ot = c >> 8, rem = c & 255, kk = rem >> 6, l = rem & 63;
    const int quad = l >> 4, l16 = l & 15;
    *reinterpret_cast<bf16x8*>(w2s + (size_t)c * 8) =
        ld8(w2 + (size_t)(ot * 16 + l16) * DIM + kk * 32 + quad * 8);
  }
}

// ---------------- k_fused: R0 body; x staged directly (fp32->bf16 in regs) --
// 4 windows per block, 4 waves (wave h = head h). Per thread: row sr=tid>>3
// (clamped to 24), 16-float chunk sc=tid&7 of x -> two bf16x8 fragments
// ds_written into XB at the fragment-ordered offsets (ping-pong halves).
__global__ __launch_bounds__(256, 2) void k_fused(
    const float* __restrict__ x, const short* __restrict__ w1s,
    const short* __restrict__ w2s, const float* __restrict__ qkvb,
    const float* __restrict__ pb, const float* __restrict__ combs,
    float* __restrict__ out)
{
  __shared__ __align__(16) short XB[8192];    // 2 x 512 units of 8 shorts
  __shared__ __align__(16) short TL[10240];   // 8 tiles of 32x40 shorts

  const int tid = threadIdx.x;
  const int wv = tid >> 6, l = tid & 63, l16 = l & 15, quad = l >> 4;
  const int h = wv;
  short* T1 = TL + wv * 2560;
  short* T2 = T1 + 1280;
  const int win0 = blockIdx.x * 4;
  const floatx4 zero = {0.f, 0.f, 0.f, 0.f};

  // staging geometry (uniform per thread across rounds)
  const int sr = tid >> 3, sc = tid & 7;
  const int smt = sr >> 4, sl = sr & 15, skk = sc >> 1, sq = (sc & 1) * 2;
  const int stok = (sr > 24) ? 24 : sr;
  const int ubase = (smt * 4 + skk) * 64 + sq * 16 + sl;  // 16B-unit index

  const int otl[6] = {2*h, 2*h+1, 8+2*h, 9+2*h, 16+2*h, 17+2*h};

  // persistent register weights + biases (R0 layout)
  bf16x8 w1f[6][4];
#pragma unroll
  for (int t = 0; t < 6; ++t)
#pragma unroll
    for (int kk = 0; kk < 4; ++kk)
      w1f[t][kk] = *reinterpret_cast<const bf16x8*>(
          w1s + ((size_t)(otl[t] * 4 + kk) * 64 + l) * 8);
  float qb6[6];
#pragma unroll
  for (int t = 0; t < 6; ++t) qb6[t] = qkvb[otl[t] * 16 + l16];
  float pbf[2];
#pragma unroll
  for (int nt = 0; nt < 2; ++nt) pbf[nt] = pb[h * 32 + nt * 16 + l16];

  // stage window 0 into XB half 0
  {
    const float* p = x + (size_t)win0 * 3200 + stok * 128 + sc * 16;
    float4 f0 = reinterpret_cast<const float4*>(p)[0];
    float4 f1 = reinterpret_cast<const float4*>(p)[1];
    float4 f2 = reinterpret_cast<const float4*>(p)[2];
    float4 f3 = reinterpret_cast<const float4*>(p)[3];
    bf16x8 a, b;
    a[0] = f2bs(f0.x); a[1] = f2bs(f0.y); a[2] = f2bs(f0.z); a[3] = f2bs(f0.w);
    a[4] = f2bs(f1.x); a[5] = f2bs(f1.y); a[6] = f2bs(f1.z); a[7] = f2bs(f1.w);
    b[0] = f2bs(f2.x); b[1] = f2bs(f2.y); b[2] = f2bs(f2.z); b[3] = f2bs(f2.w);
    b[4] = f2bs(f3.x); b[5] = f2bs(f3.y); b[6] = f2bs(f3.z); b[7] = f2bs(f3.w);
    *reinterpret_cast<bf16x8*>(XB + ubase * 8) = a;
    *reinterpret_cast<bf16x8*>(XB + (ubase + 16) * 8) = b;
  }

  for (int r = 0; r < 4; ++r) {
    const int win = win0 + r;
    const int g = win & 63;

    // ---- prefetches (all coalesced, independent; R0 placement) ----
    float4 xf0, xf1, xf2, xf3;
    if (r < 3) {
      const float* p = x + (size_t)(win + 1) * 3200 + stok * 128 + sc * 16;
      xf0 = reinterpret_cast<const float4*>(p)[0];
      xf1 = reinterpret_cast<const float4*>(p)[1];
      xf2 = reinterpret_cast<const float4*>(p)[2];
      xf3 = reinterpret_cast<const float4*>(p)[3];
    }
    bf16x8 w2f[2][4];
#pragma unroll
    for (int nt = 0; nt < 2; ++nt)
#pragma unroll
      for (int kk = 0; kk < 4; ++kk)
        w2f[nt][kk] = *reinterpret_cast<const bf16x8*>(
            w2s + ((size_t)((h * 2 + nt) * 4 + kk) * 64 + l) * 8);
    float cmb[2][2][4];
#pragma unroll
    for (int mt = 0; mt < 2; ++mt)
#pragma unroll
      for (int nt = 0; nt < 2; ++nt)
#pragma unroll
        for (int rr = 0; rr < 4; ++rr)
          cmb[mt][nt][rr] =
              combs[(((size_t)g * 4 + h) * 16 + mt * 8 + nt * 4 + rr) * 64 + l];

    __syncthreads();   // barrier 1: prev round's proj reads done; XB visible

    // ---- QKV: A from XB (LDS), B from registers ----
    floatx4 acc[2][6];
#pragma unroll
    for (int mt = 0; mt < 2; ++mt)
#pragma unroll
      for (int t = 0; t < 6; ++t) acc[mt][t] = zero;
#pragma unroll
    for (int kk = 0; kk < 4; ++kk) {
      const bf16x8 a0 = *reinterpret_cast<const bf16x8*>(
          XB + ((r & 1) * 512 + kk * 64 + l) * 8);
      const bf16x8 a1 = *reinterpret_cast<const bf16x8*>(
          XB + ((r & 1) * 512 + (4 + kk) * 64 + l) * 8);
#pragma unroll
      for (int t = 0; t < 6; ++t) {
        acc[0][t] = __builtin_amdgcn_mfma_f32_16x16x32_bf16(a0, w1f[t][kk], acc[0][t], 0, 0, 0);
        acc[1][t] = __builtin_amdgcn_mfma_f32_16x16x32_bf16(a1, w1f[t][kk], acc[1][t], 0, 0, 0);
      }
    }
    // epilogue: Q -> T1 [tok][d], K -> T2 [tok][d], V kept in regs
    float vres[2][2][4];
#pragma unroll
    for (int t = 0; t < 2; ++t)
#pragma unroll
      for (int mt = 0; mt < 2; ++mt)
#pragma unroll
        for (int rr = 0; rr < 4; ++rr) {
          const int row = (mt * 16 + quad * 4 + rr) * 40 + t * 16 + l16;
          T1[row] = f2bs((acc[mt][t][rr] + qb6[t]) * SCALE_Q);
          T2[row] = f2bs(acc[mt][2 + t][rr] + qb6[2 + t]);
          vres[t][mt][rr] = acc[mt][4 + t][rr] + qb6[4 + t];
        }

    // ---- attention (wave-local) ----
    bf16x8 aq[2], bk[2];
#pragma unroll
    for (int t = 0; t < 2; ++t) {
      aq[t] = *reinterpret_cast<const bf16x8*>(&T1[(t * 16 + l16) * 40 + quad * 8]);
      bk[t] = *reinterpret_cast<const bf16x8*>(&T2[(t * 16 + l16) * 40 + quad * 8]);
    }
    floatx4 S[2][2];
#pragma unroll
    for (int mt = 0; mt < 2; ++mt)
#pragma unroll
      for (int nt = 0; nt < 2; ++nt)
        S[mt][nt] = __builtin_amdgcn_mfma_f32_16x16x32_bf16(aq[mt], bk[nt], zero, 0, 0, 0);

#pragma unroll
    for (int mt = 0; mt < 2; ++mt) {
      float s[2][4];
#pragma unroll
      for (int nt = 0; nt < 2; ++nt)
#pragma unroll
        for (int rr = 0; rr < 4; ++rr) {
          const int n = nt * 16 + l16;
          s[nt][rr] = (n < 25) ? S[mt][nt][rr] + cmb[mt][nt][rr] : -1e30f;
        }
#pragma unroll
      for (int rr = 0; rr < 4; ++rr) {
        float mx = fmaxf(s[0][rr], s[1][rr]);
#pragma unroll
        for (int off = 1; off < 16; off <<= 1) mx = fmaxf(mx, __shfl_xor(mx, off));
        const float e0 = __expf(s[0][rr] - mx);
        const float e1 = __expf(s[1][rr] - mx);
        float sm = e0 + e1;
#pragma unroll
        for (int off = 1; off < 16; off <<= 1) sm += __shfl_xor(sm, off);
        const float inv = 1.f / sm;
        const int row = (mt * 16 + quad * 4 + rr) * 40;
        T2[row + l16]      = f2bs(e0 * inv);   // P over K (K consumed)
        T2[row + 16 + l16] = f2bs(e1 * inv);
      }
    }
    // VT over Q in T1 (Q consumed): [d][tok], packed 4 tokens per store
#pragma unroll
    for (int t = 0; t < 2; ++t)
#pragma unroll
      for (int mt = 0; mt < 2; ++mt) {
        short4 pk;
        pk.x = f2bs(vres[t][mt][0]); pk.y = f2bs(vres[t][mt][1]);
        pk.z = f2bs(vres[t][mt][2]); pk.w = f2bs(vres[t][mt][3]);
        *reinterpret_cast<short4*>(&T1[(t * 16 + l16) * 40 + mt * 16 + quad * 4]) = pk;
      }
    bf16x8 ap[2], bv[2];
#pragma unroll
    for (int t = 0; t < 2; ++t) {
      ap[t] = *reinterpret_cast<const bf16x8*>(&T2[(t * 16 + l16) * 40 + quad * 8]);
      bv[t] = *reinterpret_cast<const bf16x8*>(&T1[(t * 16 + l16) * 40 + quad * 8]);
    }
    floatx4 O[2][2];
#pragma unroll
    for (int mt = 0; mt < 2; ++mt)
#pragma unroll
      for (int nt = 0; nt < 2; ++nt)
        O[mt][nt] = __builtin_amdgcn_mfma_f32_16x16x32_bf16(ap[mt], bv[nt], zero, 0, 0, 0);
    // O over VT in T1: [tok][d_local]
#pragma unroll
    for (int mt = 0; mt < 2; ++mt)
#pragma unroll
      for (int rr = 0; rr < 4; ++rr)
#pragma unroll
        for (int nt = 0; nt < 2; ++nt)
          T1[(mt * 16 + quad * 4 + rr) * 40 + nt * 16 + l16] = f2bs(O[mt][nt][rr]);

    // stage next window into the other XB half (fp32 -> bf16 here)
    if (r < 3) {
      bf16x8 a, b;
      a[0] = f2bs(xf0.x); a[1] = f2bs(xf0.y); a[2] = f2bs(xf0.z); a[3] = f2bs(xf0.w);
      a[4] = f2bs(xf1.x); a[5] = f2bs(xf1.y); a[6] = f2bs(xf1.z); a[7] = f2bs(xf1.w);
      b[0] = f2bs(xf2.x); b[1] = f2bs(xf2.y); b[2] = f2bs(xf2.z); b[3] = f2bs(xf2.w);
      b[4] = f2bs(xf3.x); b[5] = f2bs(xf3.y); b[6] = f2bs(xf3.z); b[7] = f2bs(xf3.w);
      const int off = ((r + 1) & 1) * 512;
      *reinterpret_cast<bf16x8*>(XB + (off + ubase) * 8) = a;
      *reinterpret_cast<bf16x8*>(XB + (off + ubase + 16) * 8) = b;
    }
    __syncthreads();   // barrier 2: all O tiles ready, XB staged

    // ---- proj: wave h -> out cols [h*32, h*32+32) ----
    floatx4 acc2[2][2];
#pragma unroll
    for (int mt = 0; mt < 2; ++mt)
#pragma unroll
      for (int nt = 0; nt < 2; ++nt) acc2[mt][nt] = zero;
#pragma unroll
    for (int kk = 0; kk < 4; ++kk) {
      const bf16x8 a20 = *reinterpret_cast<const bf16x8*>(
          &TL[kk * 2560 + (l16) * 40 + quad * 8]);
      const bf16x8 a21 = *reinterpret_cast<const bf16x8*>(
          &TL[kk * 2560 + (16 + l16) * 40 + quad * 8]);
#pragma unroll
      for (int nt = 0; nt < 2; ++nt) {
        acc2[0][nt] = __builtin_amdgcn_mfma_f32_16x16x32_bf16(a20, w2f[nt][kk], acc2[0][nt], 0, 0, 0);
        acc2[1][nt] = __builtin_amdgcn_mfma_f32_16x16x32_bf16(a21, w2f[nt][kk], acc2[1][nt], 0, 0, 0);
      }
    }
#pragma unroll
    for (int mt = 0; mt < 2; ++mt)
#pragma unroll
      for (int rr = 0; rr < 4; ++rr) {
        const int m = mt * 16 + quad * 4 + rr;
        if (m < 25) {
#pragma unroll
          for (int nt = 0; nt < 2; ++nt)
            out[((size_t)win * NKEEP + m) * DIM + h * 32 + nt * 16 + l16] =
                acc2[mt][nt][rr] + pbf[nt];
        }
      }
  }
}

extern "C" void kernel_launch(void* const* d_in, const int* in_sizes, int n_in,
                              void* d_out, int out_size, void* d_ws, size_t ws_size,
                              hipStream_t stream) {
  const float* x    = (const float*)d_in[0];
  const float* mask = (const float*)d_in[1];
  const int*   ids  = (const int*)d_in[2];
  const float* qkvw = (const float*)d_in[3];
  const float* qkvb = (const float*)d_in[4];
  const float* pw   = (const float*)d_in[5];
  const float* pb   = (const float*)d_in[6];
  const float* btab = (const float*)d_in[7];
  const int*   rel  = (const int*)d_in[8];

  short* w1s   = (short*)d_ws;                      // 96 KB
  short* w2s   = w1s + (size_t)NW1 * 8;             // 32 KB
  float* combs = (float*)(w2s + (size_t)NW2 * 8);   // 1 MB
  float* out   = (float*)d_out;

  k_prep <<<dim3((NCB + NW1 + NW2) / 256), 256, 0, stream>>>(
      qkvw, pw, mask, ids, rel, btab, w1s, w2s, combs);
  k_fused<<<dim3(B_TOT / 4), 256, 0, stream>>>(
      x, w1s, w2s, qkvb, pb, combs, out);
}

// Round 4
// 157.504 us; speedup vs baseline: 1.7597x; 1.1452x over previous
//
#include <hip/hip_runtime.h>
#include <hip/hip_bf16.h>

typedef __attribute__((ext_vector_type(8))) short bf16x8;
typedef __attribute__((ext_vector_type(4))) float floatx4;

#define B_TOT 4096
#define NKEEP 25
#define DIM 128
#define SCALE_Q 0.17677669529663687f

#define NCB  (262144)    // 64 g * 4 h * 16 grp * 64 lane
#define NW1  (6144)      // 24 ot * 4 kk * 64 lane
#define NW2  (2048)      // 8 ot * 4 kk * 64 lane

__device__ __forceinline__ short f2bs(float f) {
  __hip_bfloat16 h = __float2bfloat16(f);
  return *reinterpret_cast<short*>(&h);
}

// XB bank-conflict swizzle: fold the per-lane-varying bits 5-7 into the
// bank-group bits 0-2. Bijective (only bits 0-2 change); applied on BOTH
// write and read sides.
__device__ __forceinline__ int swz(int u) { return u ^ ((u >> 5) & 7); }

__device__ __forceinline__ bf16x8 ld8(const float* p) {
  const float4 u = reinterpret_cast<const float4*>(p)[0];
  const float4 v = reinterpret_cast<const float4*>(p)[1];
  bf16x8 r;
  r[0] = f2bs(u.x); r[1] = f2bs(u.y); r[2] = f2bs(u.z); r[3] = f2bs(u.w);
  r[4] = f2bs(v.x); r[5] = f2bs(v.y); r[6] = f2bs(v.z); r[7] = f2bs(v.w);
  return r;
}

// ---------------- k_prep: combs + weight fragments only ----------
__global__ __launch_bounds__(256) void k_prep(
    const float* __restrict__ w1, const float* __restrict__ w2,
    const float* __restrict__ mask, const int* __restrict__ ids,
    const int* __restrict__ rel, const float* __restrict__ btab,
    short* __restrict__ w1s, short* __restrict__ w2s,
    float* __restrict__ combs)
{
  const int t = blockIdx.x * 256 + threadIdx.x;
  if (t < NCB) {
    const int g = t >> 12, rest = t & 4095;
    const int h = rest >> 10, j = rest & 1023;
    const int grp = j >> 6, lane = j & 63;
    const int mt = grp >> 3, nt = (grp >> 2) & 1, rr = grp & 3;
    const int quad = lane >> 4, l16 = lane & 15;
    const int m = mt * 16 + quad * 4 + rr, n = nt * 16 + l16;
    float v = 0.f;
    if (m < 25 && n < 25) {
      const int im = ids[g * 25 + m], in = ids[g * 25 + n];
      v = btab[rel[im * 49 + in] * 4 + h] + mask[((size_t)g * 49 + im) * 49 + in];
    }
    combs[t] = v;
  } else if (t < NCB + NW1) {
    const int c = t - NCB;
    const int ot = c >> 8, rem = c & 255, kk = rem >> 6, l = rem & 63;
    const int quad = l >> 4, l16 = l & 15;
    *reinterpret_cast<bf16x8*>(w1s + (size_t)c * 8) =
        ld8(w1 + (size_t)(ot * 16 + l16) * DIM + kk * 32 + quad * 8);
  } else {
    const int c = t - (NCB + NW1);
    const int ot = c >> 8, rem = c & 255, kk = rem >> 6, l = rem & 63;
    const int quad = l >> 4, l16 = l & 15;
    *reinterpret_cast<bf16x8*>(w2s + (size_t)c * 8) =
        ld8(w2 + (size_t)(ot * 16 + l16) * DIM + kk * 32 + quad * 8);
  }
}

// ---------------- k_fused: R0 body; x staged directly (fp32->bf16 in regs) --
// Changes vs R3: (1) XB accesses swizzled via swz() -> staging ds_writes go
// 8-way-conflict -> conflict-free; (2) all per-round global prefetches are
// issued AFTER barrier1, so barrier1's vmcnt(0) drain only covers prev-round
// store acks, and the x loads get a whole round of latency cover.
__global__ __launch_bounds__(256, 2) void k_fused(
    const float* __restrict__ x, const short* __restrict__ w1s,
    const short* __restrict__ w2s, const float* __restrict__ qkvb,
    const float* __restrict__ pb, const float* __restrict__ combs,
    float* __restrict__ out)
{
  __shared__ __align__(16) short XB[8192];    // 2 x 512 units of 8 shorts
  __shared__ __align__(16) short TL[10240];   // 8 tiles of 32x40 shorts

  const int tid = threadIdx.x;
  const int wv = tid >> 6, l = tid & 63, l16 = l & 15, quad = l >> 4;
  const int h = wv;
  short* T1 = TL + wv * 2560;
  short* T2 = T1 + 1280;
  const int win0 = blockIdx.x * 4;
  const floatx4 zero = {0.f, 0.f, 0.f, 0.f};

  // staging geometry (uniform per thread across rounds)
  const int sr = tid >> 3, sc = tid & 7;
  const int smt = sr >> 4, sl = sr & 15, skk = sc >> 1, sq = (sc & 1) * 2;
  const int stok = (sr > 24) ? 24 : sr;
  const int ubase = (smt * 4 + skk) * 64 + sq * 16 + sl;  // 16B-unit index

  const int otl[6] = {2*h, 2*h+1, 8+2*h, 9+2*h, 16+2*h, 17+2*h};

  // persistent register weights + biases
  bf16x8 w1f[6][4];
#pragma unroll
  for (int t = 0; t < 6; ++t)
#pragma unroll
    for (int kk = 0; kk < 4; ++kk)
      w1f[t][kk] = *reinterpret_cast<const bf16x8*>(
          w1s + ((size_t)(otl[t] * 4 + kk) * 64 + l) * 8);
  float qb6[6];
#pragma unroll
  for (int t = 0; t < 6; ++t) qb6[t] = qkvb[otl[t] * 16 + l16];
  float pbf[2];
#pragma unroll
  for (int nt = 0; nt < 2; ++nt) pbf[nt] = pb[h * 32 + nt * 16 + l16];

  // stage window 0 into XB half 0
  {
    const float* p = x + (size_t)win0 * 3200 + stok * 128 + sc * 16;
    float4 f0 = reinterpret_cast<const float4*>(p)[0];
    float4 f1 = reinterpret_cast<const float4*>(p)[1];
    float4 f2 = reinterpret_cast<const float4*>(p)[2];
    float4 f3 = reinterpret_cast<const float4*>(p)[3];
    bf16x8 a, b;
    a[0] = f2bs(f0.x); a[1] = f2bs(f0.y); a[2] = f2bs(f0.z); a[3] = f2bs(f0.w);
    a[4] = f2bs(f1.x); a[5] = f2bs(f1.y); a[6] = f2bs(f1.z); a[7] = f2bs(f1.w);
    b[0] = f2bs(f2.x); b[1] = f2bs(f2.y); b[2] = f2bs(f2.z); b[3] = f2bs(f2.w);
    b[4] = f2bs(f3.x); b[5] = f2bs(f3.y); b[6] = f2bs(f3.z); b[7] = f2bs(f3.w);
    *reinterpret_cast<bf16x8*>(XB + swz(ubase) * 8) = a;
    *reinterpret_cast<bf16x8*>(XB + swz(ubase + 16) * 8) = b;
  }

  for (int r = 0; r < 4; ++r) {
    const int win = win0 + r;
    const int g = win & 63;

    __syncthreads();   // barrier 1: prev round's proj reads done; XB visible
                       // (no loads outstanding except prev out-store acks)

    // ---- A fragments from XB first (LDS only) ----
    bf16x8 aW[2][4];
#pragma unroll
    for (int kk = 0; kk < 4; ++kk) {
      const int base = (r & 1) * 512;
      aW[0][kk] = *reinterpret_cast<const bf16x8*>(XB + swz(base + kk * 64 + l) * 8);
      aW[1][kk] = *reinterpret_cast<const bf16x8*>(XB + swz(base + (4 + kk) * 64 + l) * 8);
    }

    // ---- prefetches issued NOW (post-barrier): consumed much later ----
    float4 xf0, xf1, xf2, xf3;
    if (r < 3) {
      const float* p = x + (size_t)(win + 1) * 3200 + stok * 128 + sc * 16;
      xf0 = reinterpret_cast<const float4*>(p)[0];
      xf1 = reinterpret_cast<const float4*>(p)[1];
      xf2 = reinterpret_cast<const float4*>(p)[2];
      xf3 = reinterpret_cast<const float4*>(p)[3];
    }
    bf16x8 w2f[2][4];
#pragma unroll
    for (int nt = 0; nt < 2; ++nt)
#pragma unroll
      for (int kk = 0; kk < 4; ++kk)
        w2f[nt][kk] = *reinterpret_cast<const bf16x8*>(
            w2s + ((size_t)((h * 2 + nt) * 4 + kk) * 64 + l) * 8);
    float cmb[2][2][4];
#pragma unroll
    for (int mt = 0; mt < 2; ++mt)
#pragma unroll
      for (int nt = 0; nt < 2; ++nt)
#pragma unroll
        for (int rr = 0; rr < 4; ++rr)
          cmb[mt][nt][rr] =
              combs[(((size_t)g * 4 + h) * 16 + mt * 8 + nt * 4 + rr) * 64 + l];

    // ---- QKV: A from XB (registers), B from registers ----
    floatx4 acc[2][6];
#pragma unroll
    for (int mt = 0; mt < 2; ++mt)
#pragma unroll
      for (int t = 0; t < 6; ++t) acc[mt][t] = zero;
#pragma unroll
    for (int kk = 0; kk < 4; ++kk) {
#pragma unroll
      for (int t = 0; t < 6; ++t) {
        acc[0][t] = __builtin_amdgcn_mfma_f32_16x16x32_bf16(aW[0][kk], w1f[t][kk], acc[0][t], 0, 0, 0);
        acc[1][t] = __builtin_amdgcn_mfma_f32_16x16x32_bf16(aW[1][kk], w1f[t][kk], acc[1][t], 0, 0, 0);
      }
    }
    // epilogue: Q -> T1 [tok][d], K -> T2 [tok][d], V kept in regs
    float vres[2][2][4];
#pragma unroll
    for (int t = 0; t < 2; ++t)
#pragma unroll
      for (int mt = 0; mt < 2; ++mt)
#pragma unroll
        for (int rr = 0; rr < 4; ++rr) {
          const int row = (mt * 16 + quad * 4 + rr) * 40 + t * 16 + l16;
          T1[row] = f2bs((acc[mt][t][rr] + qb6[t]) * SCALE_Q);
          T2[row] = f2bs(acc[mt][2 + t][rr] + qb6[2 + t]);
          vres[t][mt][rr] = acc[mt][4 + t][rr] + qb6[4 + t];
        }

    // ---- attention (wave-local) ----
    bf16x8 aq[2], bk[2];
#pragma unroll
    for (int t = 0; t < 2; ++t) {
      aq[t] = *reinterpret_cast<const bf16x8*>(&T1[(t * 16 + l16) * 40 + quad * 8]);
      bk[t] = *reinterpret_cast<const bf16x8*>(&T2[(t * 16 + l16) * 40 + quad * 8]);
    }
    floatx4 S[2][2];
#pragma unroll
    for (int mt = 0; mt < 2; ++mt)
#pragma unroll
      for (int nt = 0; nt < 2; ++nt)
        S[mt][nt] = __builtin_amdgcn_mfma_f32_16x16x32_bf16(aq[mt], bk[nt], zero, 0, 0, 0);

#pragma unroll
    for (int mt = 0; mt < 2; ++mt) {
      float s[2][4];
#pragma unroll
      for (int nt = 0; nt < 2; ++nt)
#pragma unroll
        for (int rr = 0; rr < 4; ++rr) {
          const int n = nt * 16 + l16;
          s[nt][rr] = (n < 25) ? S[mt][nt][rr] + cmb[mt][nt][rr] : -1e30f;
        }
#pragma unroll
      for (int rr = 0; rr < 4; ++rr) {
        float mx = fmaxf(s[0][rr], s[1][rr]);
#pragma unroll
        for (int off = 1; off < 16; off <<= 1) mx = fmaxf(mx, __shfl_xor(mx, off));
        const float e0 = __expf(s[0][rr] - mx);
        const float e1 = __expf(s[1][rr] - mx);
        float sm = e0 + e1;
#pragma unroll
        for (int off = 1; off < 16; off <<= 1) sm += __shfl_xor(sm, off);
        const float inv = 1.f / sm;
        const int row = (mt * 16 + quad * 4 + rr) * 40;
        T2[row + l16]      = f2bs(e0 * inv);   // P over K (K consumed)
        T2[row + 16 + l16] = f2bs(e1 * inv);
      }
    }
    // VT over Q in T1 (Q consumed): [d][tok], packed 4 tokens per store
#pragma unroll
    for (int t = 0; t < 2; ++t)
#pragma unroll
      for (int mt = 0; mt < 2; ++mt) {
        short4 pk;
        pk.x = f2bs(vres[t][mt][0]); pk.y = f2bs(vres[t][mt][1]);
        pk.z = f2bs(vres[t][mt][2]); pk.w = f2bs(vres[t][mt][3]);
        *reinterpret_cast<short4*>(&T1[(t * 16 + l16) * 40 + mt * 16 + quad * 4]) = pk;
      }
    bf16x8 ap[2], bv[2];
#pragma unroll
    for (int t = 0; t < 2; ++t) {
      ap[t] = *reinterpret_cast<const bf16x8*>(&T2[(t * 16 + l16) * 40 + quad * 8]);
      bv[t] = *reinterpret_cast<const bf16x8*>(&T1[(t * 16 + l16) * 40 + quad * 8]);
    }
    floatx4 O[2][2];
#pragma unroll
    for (int mt = 0; mt < 2; ++mt)
#pragma unroll
      for (int nt = 0; nt < 2; ++nt)
        O[mt][nt] = __builtin_amdgcn_mfma_f32_16x16x32_bf16(ap[mt], bv[nt], zero, 0, 0, 0);
    // O over VT in T1: [tok][d_local]
#pragma unroll
    for (int mt = 0; mt < 2; ++mt)
#pragma unroll
      for (int rr = 0; rr < 4; ++rr)
#pragma unroll
        for (int nt = 0; nt < 2; ++nt)
          T1[(mt * 16 + quad * 4 + rr) * 40 + nt * 16 + l16] = f2bs(O[mt][nt][rr]);

    // stage next window into the other XB half (fp32 -> bf16 here; the
    // vmcnt wait for xf* lands HERE, ~a full round after issue)
    if (r < 3) {
      bf16x8 a, b;
      a[0] = f2bs(xf0.x); a[1] = f2bs(xf0.y); a[2] = f2bs(xf0.z); a[3] = f2bs(xf0.w);
      a[4] = f2bs(xf1.x); a[5] = f2bs(xf1.y); a[6] = f2bs(xf1.z); a[7] = f2bs(xf1.w);
      b[0] = f2bs(xf2.x); b[1] = f2bs(xf2.y); b[2] = f2bs(xf2.z); b[3] = f2bs(xf2.w);
      b[4] = f2bs(xf3.x); b[5] = f2bs(xf3.y); b[6] = f2bs(xf3.w == xf3.w ? xf3.z : xf3.z); b[7] = f2bs(xf3.w);
      b[6] = f2bs(xf3.z);
      const int off = ((r + 1) & 1) * 512;
      *reinterpret_cast<bf16x8*>(XB + swz(off + ubase) * 8) = a;
      *reinterpret_cast<bf16x8*>(XB + swz(off + ubase + 16) * 8) = b;
    }
    __syncthreads();   // barrier 2: all O tiles ready, XB staged

    // ---- proj: wave h -> out cols [h*32, h*32+32) ----
    floatx4 acc2[2][2];
#pragma unroll
    for (int mt = 0; mt < 2; ++mt)
#pragma unroll
      for (int nt = 0; nt < 2; ++nt) acc2[mt][nt] = zero;
#pragma unroll
    for (int kk = 0; kk < 4; ++kk) {
      const bf16x8 a20 = *reinterpret_cast<const bf16x8*>(
          &TL[kk * 2560 + (l16) * 40 + quad * 8]);
      const bf16x8 a21 = *reinterpret_cast<const bf16x8*>(
          &TL[kk * 2560 + (16 + l16) * 40 + quad * 8]);
#pragma unroll
      for (int nt = 0; nt < 2; ++nt) {
        acc2[0][nt] = __builtin_amdgcn_mfma_f32_16x16x32_bf16(a20, w2f[nt][kk], acc2[0][nt], 0, 0, 0);
        acc2[1][nt] = __builtin_amdgcn_mfma_f32_16x16x32_bf16(a21, w2f[nt][kk], acc2[1][nt], 0, 0, 0);
      }
    }
#pragma unroll
    for (int mt = 0; mt < 2; ++mt)
#pragma unroll
      for (int rr = 0; rr < 4; ++rr) {
        const int m = mt * 16 + quad * 4 + rr;
        if (m < 25) {
#pragma unroll
          for (int nt = 0; nt < 2; ++nt)
            out[((size_t)win * NKEEP + m) * DIM + h * 32 + nt * 16 + l16] =
                acc2[mt][nt][rr] + pbf[nt];
        }
      }
  }
}

extern "C" void kernel_launch(void* const* d_in, const int* in_sizes, int n_in,
                              void* d_out, int out_size, void* d_ws, size_t ws_size,
                              hipStream_t stream) {
  const float* x    = (const float*)d_in[0];
  const float* mask = (const float*)d_in[1];
  const int*   ids  = (const int*)d_in[2];
  const float* qkvw = (const float*)d_in[3];
  const float* qkvb = (const float*)d_in[4];
  const float* pw   = (const float*)d_in[5];
  const float* pb   = (const float*)d_in[6];
  const float* btab = (const float*)d_in[7];
  const int*   rel  = (const int*)d_in[8];

  short* w1s   = (short*)d_ws;                      // 96 KB
  short* w2s   = w1s + (size_t)NW1 * 8;             // 32 KB
  float* combs = (float*)(w2s + (size_t)NW2 * 8);   // 1 MB
  float* out   = (float*)d_out;

  k_prep <<<dim3((NCB + NW1 + NW2) / 256), 256, 0, stream>>>(
      qkvw, pw, mask, ids, rel, btab, w1s, w2s, combs);
  k_fused<<<dim3(B_TOT / 4), 256, 0, stream>>>(
      x, w1s, w2s, qkvb, pb, combs, out);
}

// Round 5
// 137.744 us; speedup vs baseline: 2.0121x; 1.1435x over previous
//
#include <hip/hip_runtime.h>
#include <hip/hip_bf16.h>

typedef __attribute__((ext_vector_type(8))) short bf16x8;
typedef __attribute__((ext_vector_type(4))) float floatx4;

#define B_TOT 4096
#define NKEEP 25
#define DIM 128
#define SCALE_Q 0.17677669529663687f

#define NCB  (262144)    // 64 g * 4 h * 16 grp * 64 lane
#define NW1  (6144)      // 24 ot * 4 kk * 64 lane
#define NW2  (2048)      // 8 ot * 4 kk * 64 lane

__device__ __forceinline__ short f2bs(float f) {
  __hip_bfloat16 h = __float2bfloat16(f);
  return *reinterpret_cast<short*>(&h);
}

// XB bank-conflict swizzle: fold the per-lane-varying bits 5-7 into the
// bank-group bits 0-2. Bijective; applied on BOTH write and read sides.
__device__ __forceinline__ int swz(int u) { return u ^ ((u >> 5) & 7); }

__device__ __forceinline__ bf16x8 ld8(const float* p) {
  const float4 u = reinterpret_cast<const float4*>(p)[0];
  const float4 v = reinterpret_cast<const float4*>(p)[1];
  bf16x8 r;
  r[0] = f2bs(u.x); r[1] = f2bs(u.y); r[2] = f2bs(u.z); r[3] = f2bs(u.w);
  r[4] = f2bs(v.x); r[5] = f2bs(v.y); r[6] = f2bs(v.z); r[7] = f2bs(v.w);
  return r;
}

// ---------------- k_prep: combs + weight fragments only ----------
// combs layout matches the SWAPPED-S lane mapping in k_fused:
// entry (g,h,grp=(mt,nt,rr),lane=(quad,l16)) holds bias+mask at
// (m = mt*16 + l16, n = nt*16 + quad*4 + rr).
__global__ __launch_bounds__(256) void k_prep(
    const float* __restrict__ w1, const float* __restrict__ w2,
    const float* __restrict__ mask, const int* __restrict__ ids,
    const int* __restrict__ rel, const float* __restrict__ btab,
    short* __restrict__ w1s, short* __restrict__ w2s,
    float* __restrict__ combs)
{
  const int t = blockIdx.x * 256 + threadIdx.x;
  if (t < NCB) {
    const int g = t >> 12, rest = t & 4095;
    const int h = rest >> 10, j = rest & 1023;
    const int grp = j >> 6, lane = j & 63;
    const int mt = grp >> 3, nt = (grp >> 2) & 1, rr = grp & 3;
    const int quad = lane >> 4, l16 = lane & 15;
    const int m = mt * 16 + l16, n = nt * 16 + quad * 4 + rr;   // swapped-S map
    float v = 0.f;
    if (m < 25 && n < 25) {
      const int im = ids[g * 25 + m], in = ids[g * 25 + n];
      v = btab[rel[im * 49 + in] * 4 + h] + mask[((size_t)g * 49 + im) * 49 + in];
    }
    combs[t] = v;
  } else if (t < NCB + NW1) {
    const int c = t - NCB;
    const int ot = c >> 8, rem = c & 255, kk = rem >> 6, l = rem & 63;
    const int quad = l >> 4, l16 = l & 15;
    *reinterpret_cast<bf16x8*>(w1s + (size_t)c * 8) =
        ld8(w1 + (size_t)(ot * 16 + l16) * DIM + kk * 32 + quad * 8);
  } else {
    const int c = t - (NCB + NW1);
    const int ot = c >> 8, rem = c & 255, kk = rem >> 6, l = rem & 63;
    const int quad = l >> 4, l16 = l & 15;
    *reinterpret_cast<bf16x8*>(w2s + (size_t)c * 8) =
        ld8(w2 + (size_t)(ot * 16 + l16) * DIM + kk * 32 + quad * 8);
  }
}

// ---------------- k_fused -------------------------------------------------
// R4 base. Change: SWAPPED QK^T — St[nt][mt] = mfma(K-tile, Q-tile), so lane
// (quad,l16) holds q-row q=mt*16+l16 with 8 k-values (nt,rr). Row softmax is
// 7 fmax + 2 shfl (+ 7 add + 2 shfl), i.e. 8 cross-lane ops/thread/round
// instead of 64; one reciprocal per row; P stored as packed short4. T2's
// consumed layout P[q][k] is unchanged -> PV/proj untouched.
__global__ __launch_bounds__(256, 2) void k_fused(
    const float* __restrict__ x, const short* __restrict__ w1s,
    const short* __restrict__ w2s, const float* __restrict__ qkvb,
    const float* __restrict__ pb, const float* __restrict__ combs,
    float* __restrict__ out)
{
  __shared__ __align__(16) short XB[8192];    // 2 x 512 units of 8 shorts
  __shared__ __align__(16) short TL[10240];   // 8 tiles of 32x40 shorts

  const int tid = threadIdx.x;
  const int wv = tid >> 6, l = tid & 63, l16 = l & 15, quad = l >> 4;
  const int h = wv;
  short* T1 = TL + wv * 2560;
  short* T2 = T1 + 1280;
  const int win0 = blockIdx.x * 4;
  const floatx4 zero = {0.f, 0.f, 0.f, 0.f};

  // staging geometry (uniform per thread across rounds)
  const int sr = tid >> 3, sc = tid & 7;
  const int smt = sr >> 4, sl = sr & 15, skk = sc >> 1, sq = (sc & 1) * 2;
  const int stok = (sr > 24) ? 24 : sr;
  const int ubase = (smt * 4 + skk) * 64 + sq * 16 + sl;  // 16B-unit index

  const int otl[6] = {2*h, 2*h+1, 8+2*h, 9+2*h, 16+2*h, 17+2*h};

  // persistent register weights + biases
  bf16x8 w1f[6][4];
#pragma unroll
  for (int t = 0; t < 6; ++t)
#pragma unroll
    for (int kk = 0; kk < 4; ++kk)
      w1f[t][kk] = *reinterpret_cast<const bf16x8*>(
          w1s + ((size_t)(otl[t] * 4 + kk) * 64 + l) * 8);
  float qb6[6];
#pragma unroll
  for (int t = 0; t < 6; ++t) qb6[t] = qkvb[otl[t] * 16 + l16];
  float pbf[2];
#pragma unroll
  for (int nt = 0; nt < 2; ++nt) pbf[nt] = pb[h * 32 + nt * 16 + l16];

  // stage window 0 into XB half 0
  {
    const float* p = x + (size_t)win0 * 3200 + stok * 128 + sc * 16;
    float4 f0 = reinterpret_cast<const float4*>(p)[0];
    float4 f1 = reinterpret_cast<const float4*>(p)[1];
    float4 f2 = reinterpret_cast<const float4*>(p)[2];
    float4 f3 = reinterpret_cast<const float4*>(p)[3];
    bf16x8 a, b;
    a[0] = f2bs(f0.x); a[1] = f2bs(f0.y); a[2] = f2bs(f0.z); a[3] = f2bs(f0.w);
    a[4] = f2bs(f1.x); a[5] = f2bs(f1.y); a[6] = f2bs(f1.z); a[7] = f2bs(f1.w);
    b[0] = f2bs(f2.x); b[1] = f2bs(f2.y); b[2] = f2bs(f2.z); b[3] = f2bs(f2.w);
    b[4] = f2bs(f3.x); b[5] = f2bs(f3.y); b[6] = f2bs(f3.z); b[7] = f2bs(f3.w);
    *reinterpret_cast<bf16x8*>(XB + swz(ubase) * 8) = a;
    *reinterpret_cast<bf16x8*>(XB + swz(ubase + 16) * 8) = b;
  }

  for (int r = 0; r < 4; ++r) {
    const int win = win0 + r;
    const int g = win & 63;

    __syncthreads();   // barrier 1: prev round's proj reads done; XB visible

    // ---- A fragments from XB first (LDS only) ----
    bf16x8 aW[2][4];
#pragma unroll
    for (int kk = 0; kk < 4; ++kk) {
      const int base = (r & 1) * 512;
      aW[0][kk] = *reinterpret_cast<const bf16x8*>(XB + swz(base + kk * 64 + l) * 8);
      aW[1][kk] = *reinterpret_cast<const bf16x8*>(XB + swz(base + (4 + kk) * 64 + l) * 8);
    }

    // ---- prefetches issued NOW (post-barrier): consumed much later ----
    float4 xf0, xf1, xf2, xf3;
    if (r < 3) {
      const float* p = x + (size_t)(win + 1) * 3200 + stok * 128 + sc * 16;
      xf0 = reinterpret_cast<const float4*>(p)[0];
      xf1 = reinterpret_cast<const float4*>(p)[1];
      xf2 = reinterpret_cast<const float4*>(p)[2];
      xf3 = reinterpret_cast<const float4*>(p)[3];
    }
    bf16x8 w2f[2][4];
#pragma unroll
    for (int nt = 0; nt < 2; ++nt)
#pragma unroll
      for (int kk = 0; kk < 4; ++kk)
        w2f[nt][kk] = *reinterpret_cast<const bf16x8*>(
            w2s + ((size_t)((h * 2 + nt) * 4 + kk) * 64 + l) * 8);
    float cmb[2][2][4];
#pragma unroll
    for (int mt = 0; mt < 2; ++mt)
#pragma unroll
      for (int nt = 0; nt < 2; ++nt)
#pragma unroll
        for (int rr = 0; rr < 4; ++rr)
          cmb[mt][nt][rr] =
              combs[(((size_t)g * 4 + h) * 16 + mt * 8 + nt * 4 + rr) * 64 + l];

    // ---- QKV: A from XB (registers), B from registers ----
    floatx4 acc[2][6];
#pragma unroll
    for (int mt = 0; mt < 2; ++mt)
#pragma unroll
      for (int t = 0; t < 6; ++t) acc[mt][t] = zero;
#pragma unroll
    for (int kk = 0; kk < 4; ++kk) {
#pragma unroll
      for (int t = 0; t < 6; ++t) {
        acc[0][t] = __builtin_amdgcn_mfma_f32_16x16x32_bf16(aW[0][kk], w1f[t][kk], acc[0][t], 0, 0, 0);
        acc[1][t] = __builtin_amdgcn_mfma_f32_16x16x32_bf16(aW[1][kk], w1f[t][kk], acc[1][t], 0, 0, 0);
      }
    }
    // epilogue: Q -> T1 [tok][d], K -> T2 [tok][d], V kept in regs
    float vres[2][2][4];
#pragma unroll
    for (int t = 0; t < 2; ++t)
#pragma unroll
      for (int mt = 0; mt < 2; ++mt)
#pragma unroll
        for (int rr = 0; rr < 4; ++rr) {
          const int row = (mt * 16 + quad * 4 + rr) * 40 + t * 16 + l16;
          T1[row] = f2bs((acc[mt][t][rr] + qb6[t]) * SCALE_Q);
          T2[row] = f2bs(acc[mt][2 + t][rr] + qb6[2 + t]);
          vres[t][mt][rr] = acc[mt][4 + t][rr] + qb6[4 + t];
        }

    // ---- attention (wave-local), SWAPPED QK^T ----
    bf16x8 aq[2], bk[2];
#pragma unroll
    for (int t = 0; t < 2; ++t) {
      aq[t] = *reinterpret_cast<const bf16x8*>(&T1[(t * 16 + l16) * 40 + quad * 8]);
      bk[t] = *reinterpret_cast<const bf16x8*>(&T2[(t * 16 + l16) * 40 + quad * 8]);
    }
    // St[nt][mt][rr]: q = mt*16 + l16 (col), k = nt*16 + quad*4 + rr (row)
    floatx4 St[2][2];
#pragma unroll
    for (int nt = 0; nt < 2; ++nt)
#pragma unroll
      for (int mt = 0; mt < 2; ++mt)
        St[nt][mt] = __builtin_amdgcn_mfma_f32_16x16x32_bf16(bk[nt], aq[mt], zero, 0, 0, 0);

#pragma unroll
    for (int mt = 0; mt < 2; ++mt) {
      float v[2][4];
      float mx = -1e30f;
#pragma unroll
      for (int nt = 0; nt < 2; ++nt)
#pragma unroll
        for (int rr = 0; rr < 4; ++rr) {
          const int kidx = nt * 16 + quad * 4 + rr;
          v[nt][rr] = (kidx < 25) ? St[nt][mt][rr] + cmb[mt][nt][rr] : -1e30f;
          mx = fmaxf(mx, v[nt][rr]);
        }
      mx = fmaxf(mx, __shfl_xor(mx, 16));
      mx = fmaxf(mx, __shfl_xor(mx, 32));
      float e[2][4];
      float sm = 0.f;
#pragma unroll
      for (int nt = 0; nt < 2; ++nt)
#pragma unroll
        for (int rr = 0; rr < 4; ++rr) {
          e[nt][rr] = __expf(v[nt][rr] - mx);
          sm += e[nt][rr];
        }
      sm += __shfl_xor(sm, 16);
      sm += __shfl_xor(sm, 32);
      const float inv = 1.f / sm;
      // P[q = mt*16+l16][k = nt*16+quad*4 .. +3] packed (K tile consumed)
#pragma unroll
      for (int nt = 0; nt < 2; ++nt) {
        short4 pk;
        pk.x = f2bs(e[nt][0] * inv);
        pk.y = f2bs(e[nt][1] * inv);
        pk.z = f2bs(e[nt][2] * inv);
        pk.w = f2bs(e[nt][3] * inv);
        *reinterpret_cast<short4*>(&T2[(mt * 16 + l16) * 40 + nt * 16 + quad * 4]) = pk;
      }
    }
    // VT over Q in T1 (Q consumed): [d][tok], packed 4 tokens per store
#pragma unroll
    for (int t = 0; t < 2; ++t)
#pragma unroll
      for (int mt = 0; mt < 2; ++mt) {
        short4 pk;
        pk.x = f2bs(vres[t][mt][0]); pk.y = f2bs(vres[t][mt][1]);
        pk.z = f2bs(vres[t][mt][2]); pk.w = f2bs(vres[t][mt][3]);
        *reinterpret_cast<short4*>(&T1[(t * 16 + l16) * 40 + mt * 16 + quad * 4]) = pk;
      }
    bf16x8 ap[2], bv[2];
#pragma unroll
    for (int t = 0; t < 2; ++t) {
      ap[t] = *reinterpret_cast<const bf16x8*>(&T2[(t * 16 + l16) * 40 + quad * 8]);
      bv[t] = *reinterpret_cast<const bf16x8*>(&T1[(t * 16 + l16) * 40 + quad * 8]);
    }
    floatx4 O[2][2];
#pragma unroll
    for (int mt = 0; mt < 2; ++mt)
#pragma unroll
      for (int nt = 0; nt < 2; ++nt)
        O[mt][nt] = __builtin_amdgcn_mfma_f32_16x16x32_bf16(ap[mt], bv[nt], zero, 0, 0, 0);
    // O over VT in T1: [tok][d_local]
#pragma unroll
    for (int mt = 0; mt < 2; ++mt)
#pragma unroll
      for (int rr = 0; rr < 4; ++rr)
#pragma unroll
        for (int nt = 0; nt < 2; ++nt)
          T1[(mt * 16 + quad * 4 + rr) * 40 + nt * 16 + l16] = f2bs(O[mt][nt][rr]);

    // stage next window into the other XB half (fp32 -> bf16 here; the
    // vmcnt wait for xf* lands HERE, ~a full round after issue)
    if (r < 3) {
      bf16x8 a, b;
      a[0] = f2bs(xf0.x); a[1] = f2bs(xf0.y); a[2] = f2bs(xf0.z); a[3] = f2bs(xf0.w);
      a[4] = f2bs(xf1.x); a[5] = f2bs(xf1.y); a[6] = f2bs(xf1.z); a[7] = f2bs(xf1.w);
      b[0] = f2bs(xf2.x); b[1] = f2bs(xf2.y); b[2] = f2bs(xf2.z); b[3] = f2bs(xf2.w);
      b[4] = f2bs(xf3.x); b[5] = f2bs(xf3.y); b[6] = f2bs(xf3.z); b[7] = f2bs(xf3.w);
      const int off = ((r + 1) & 1) * 512;
      *reinterpret_cast<bf16x8*>(XB + swz(off + ubase) * 8) = a;
      *reinterpret_cast<bf16x8*>(XB + swz(off + ubase + 16) * 8) = b;
    }
    __syncthreads();   // barrier 2: all O tiles ready, XB staged

    // ---- proj: wave h -> out cols [h*32, h*32+32) ----
    floatx4 acc2[2][2];
#pragma unroll
    for (int mt = 0; mt < 2; ++mt)
#pragma unroll
      for (int nt = 0; nt < 2; ++nt) acc2[mt][nt] = zero;
#pragma unroll
    for (int kk = 0; kk < 4; ++kk) {
      const bf16x8 a20 = *reinterpret_cast<const bf16x8*>(
          &TL[kk * 2560 + (l16) * 40 + quad * 8]);
      const bf16x8 a21 = *reinterpret_cast<const bf16x8*>(
          &TL[kk * 2560 + (16 + l16) * 40 + quad * 8]);
#pragma unroll
      for (int nt = 0; nt < 2; ++nt) {
        acc2[0][nt] = __builtin_amdgcn_mfma_f32_16x16x32_bf16(a20, w2f[nt][kk], acc2[0][nt], 0, 0, 0);
        acc2[1][nt] = __builtin_amdgcn_mfma_f32_16x16x32_bf16(a21, w2f[nt][kk], acc2[1][nt], 0, 0, 0);
      }
    }
#pragma unroll
    for (int mt = 0; mt < 2; ++mt)
#pragma unroll
      for (int rr = 0; rr < 4; ++rr) {
        const int m = mt * 16 + quad * 4 + rr;
        if (m < 25) {
#pragma unroll
          for (int nt = 0; nt < 2; ++nt)
            out[((size_t)win * NKEEP + m) * DIM + h * 32 + nt * 16 + l16] =
                acc2[mt][nt][rr] + pbf[nt];
        }
      }
  }
}

extern "C" void kernel_launch(void* const* d_in, const int* in_sizes, int n_in,
                              void* d_out, int out_size, void* d_ws, size_t ws_size,
                              hipStream_t stream) {
  const float* x    = (const float*)d_in[0];
  const float* mask = (const float*)d_in[1];
  const int*   ids  = (const int*)d_in[2];
  const float* qkvw = (const float*)d_in[3];
  const float* qkvb = (const float*)d_in[4];
  const float* pw   = (const float*)d_in[5];
  const float* pb   = (const float*)d_in[6];
  const float* btab = (const float*)d_in[7];
  const int*   rel  = (const int*)d_in[8];

  short* w1s   = (short*)d_ws;                      // 96 KB
  short* w2s   = w1s + (size_t)NW1 * 8;             // 32 KB
  float* combs = (float*)(w2s + (size_t)NW2 * 8);   // 1 MB
  float* out   = (float*)d_out;

  k_prep <<<dim3((NCB + NW1 + NW2) / 256), 256, 0, stream>>>(
      qkvw, pw, mask, ids, rel, btab, w1s, w2s, combs);
  k_fused<<<dim3(B_TOT / 4), 256, 0, stream>>>(
      x, w1s, w2s, qkvb, pb, combs, out);
}